// Round 2
// baseline (1690.587 us; speedup 1.0000x reference)
//
#include <hip/hip_runtime.h>
#include <hip/hip_bf16.h>

#define VOCAB 29
#define VEC   512
#define HID   1024
#define SEN   64
#define BATCH 2048

typedef __bf16 bf16_t;
typedef bf16_t bf16x8 __attribute__((ext_vector_type(8)));
typedef float  floatx4 __attribute__((ext_vector_type(4)));

// ---------------- prep: W_hh fp32 -> bf16 ----------------
__global__ void cvt_whh(const float* __restrict__ w, bf16_t* __restrict__ o, int n) {
    int i = blockIdx.x * blockDim.x + threadIdx.x;
    if (i < n) o[i] = (bf16_t)w[i];
}

// ---------------- prep: W_cls fp32 [65][1024] -> bf16 padded [80][1024] ----------------
__global__ void cvt_wcls(const float* __restrict__ w, bf16_t* __restrict__ o) {
    int i = blockIdx.x * blockDim.x + threadIdx.x;
    if (i >= 80 * HID) return;
    o[i] = (i < 65 * HID) ? (bf16_t)w[i] : (bf16_t)0.0f;
}

// ---------------- prep: proj[v][h] = dot(emb[v], W_ih[h]) (fp32) ----------------
__global__ void proj_kernel(const float* __restrict__ emb, const float* __restrict__ wih,
                            float* __restrict__ proj) {
    int idx = blockIdx.x * blockDim.x + threadIdx.x;
    if (idx >= VOCAB * HID) return;
    int v = idx / HID, h = idx % HID;
    const float* e = emb + v * VEC;
    const float* w = wih + h * VEC;
    float s = 0.f;
    for (int k = 0; k < VEC; k += 4) {
        float4 ev = *(const float4*)(e + k);
        float4 wv = *(const float4*)(w + k);
        s += ev.x * wv.x + ev.y * wv.y + ev.z * wv.z + ev.w * wv.w;
    }
    proj[idx] = s;
}

// exact identity tanh(x) = 1 - 2/(exp(2x)+1); fp32 rounding error << bf16 ulp
__device__ __forceinline__ float fast_tanh(float x) {
    float e = __expf(2.0f * x);
    return 1.0f - 2.0f / (e + 1.0f);
}

// async global->LDS 16B copy. LDS dest: wave-uniform base + lane*16 (HW rule).
__device__ __forceinline__ void load16_to_lds(const bf16_t* g, bf16_t* l) {
    auto gp = reinterpret_cast<const __attribute__((address_space(1))) unsigned int*>(
        reinterpret_cast<uintptr_t>(g));
    auto lp = reinterpret_cast<__attribute__((address_space(3))) unsigned int*>(
        static_cast<unsigned int>(reinterpret_cast<uintptr_t>(l)));
    __builtin_amdgcn_global_load_lds(gp, lp, 16, 0, 0);
}

// ============================================================================
// v3: PERSISTENT RNN. One kernel runs all 64 timesteps.
//   - W_hh slice [BN=64][HID] staged to LDS ONCE (128 KB; was 128 KB *per step*).
//   - A (h rows) read global->VGPR in MFMA fragment layout, double-buffered
//     8-chunk groups. vmem queue per step holds ONLY A/tok/proj loads (the v2
//     regression was A-prefetch FIFO-coupled behind per-step B-DMA bursts).
//   - Cross-block step dependency: hand-rolled grid sync (device-scope
//     release add + acquire spin). Co-residency structural: 256 blocks x
//     128 KB LDS = 1 block/CU on 256 CUs. Graph-capture-safe.
//   - 63 syncs replace 64 launches (+gaps, +per-step staging, +2 drains/step).
// ============================================================================
#define BM 128
#define BN 64
#define NBLK 256

__device__ __forceinline__ void grid_sync_slot(int* cnt) {
    __syncthreads();   // block's stores/loads for this step done (vmcnt drain)
    if (threadIdx.x == 0) {
        __hip_atomic_fetch_add(cnt, 1, __ATOMIC_RELEASE, __HIP_MEMORY_SCOPE_AGENT);
        while (__hip_atomic_load(cnt, __ATOMIC_ACQUIRE, __HIP_MEMORY_SCOPE_AGENT) < NBLK)
            __builtin_amdgcn_s_sleep(2);
    }
    __syncthreads();   // release block-mates; acquire's L1/L2 inv is CU/XCD-wide
}

#define ISSUE_AF(BUF, KBASE)                                                     \
    _Pragma("unroll")                                                            \
    for (int j = 0; j < 8; j++) {                                                \
        af[BUF][j][0] = *(const bf16x8*)(hA + ((KBASE) + j) * 32);               \
        af[BUF][j][1] = *(const bf16x8*)(hA + 16 * HID + ((KBASE) + j) * 32);    \
    }

#define COMPUTE_GROUP(BUF, KBASE)                                                \
    _Pragma("unroll")                                                            \
    for (int j = 0; j < 8; j++) {                                                \
        const int p = (4 * ((KBASE) + j) + q) ^ l7;  /* phys 16B chunk in row */ \
        bf16x8 b0 = *(const bf16x8*)&Bsh[l16][p * 8];                            \
        bf16x8 b1 = *(const bf16x8*)&Bsh[16 + l16][p * 8];                       \
        bf16x8 b2 = *(const bf16x8*)&Bsh[32 + l16][p * 8];                       \
        bf16x8 b3 = *(const bf16x8*)&Bsh[48 + l16][p * 8];                       \
        acc[0][0] = __builtin_amdgcn_mfma_f32_16x16x32_bf16(af[BUF][j][0], b0, acc[0][0], 0, 0, 0); \
        acc[0][1] = __builtin_amdgcn_mfma_f32_16x16x32_bf16(af[BUF][j][0], b1, acc[0][1], 0, 0, 0); \
        acc[0][2] = __builtin_amdgcn_mfma_f32_16x16x32_bf16(af[BUF][j][0], b2, acc[0][2], 0, 0, 0); \
        acc[0][3] = __builtin_amdgcn_mfma_f32_16x16x32_bf16(af[BUF][j][0], b3, acc[0][3], 0, 0, 0); \
        acc[1][0] = __builtin_amdgcn_mfma_f32_16x16x32_bf16(af[BUF][j][1], b0, acc[1][0], 0, 0, 0); \
        acc[1][1] = __builtin_amdgcn_mfma_f32_16x16x32_bf16(af[BUF][j][1], b1, acc[1][1], 0, 0, 0); \
        acc[1][2] = __builtin_amdgcn_mfma_f32_16x16x32_bf16(af[BUF][j][1], b2, acc[1][2], 0, 0, 0); \
        acc[1][3] = __builtin_amdgcn_mfma_f32_16x16x32_bf16(af[BUF][j][1], b3, acc[1][3], 0, 0, 0); \
    }

__global__ __launch_bounds__(256, 1)
void rnn_persist(const bf16_t* __restrict__ whh, const float* __restrict__ proj,
                 const int* __restrict__ x, bf16_t* hbuf, int* sync_cnt)
{
    __shared__ __align__(16) bf16_t Bsh[BN][HID];   // exactly 128 KB -> 1 block/CU

    const int tid  = threadIdx.x;
    const int m0   = blockIdx.x * BM;
    const int n0   = blockIdx.y * BN;
    const int wave = tid >> 6;
    const int lane = tid & 63;
    const int wm   = wave * 32;        // 4 waves split m: wave tile 32 x 64
    const int q    = lane >> 4;
    const int l16  = lane & 15;
    const int l7   = l16 & 7;

    // ---- stage W_hh slice ONCE: row r per wave, 64 lanes = 64 chunks per half.
    //      Dest lane-linear (DMA rule), source chunk XOR'd: phys = glob ^ (r&7).
#pragma unroll
    for (int half = 0; half < 2; half++)
#pragma unroll
        for (int it = 0; it < 16; it++) {
            const int r = it * 4 + wave;
            load16_to_lds(whh + (n0 + r) * HID + half * 512 + (lane ^ (r & 7)) * 8,
                          &Bsh[r][half * 512 + lane * 8]);
        }
    // (drained by the __syncthreads inside the first grid_sync_slot, before first use at t=1)

    // rows this lane owns in the epilogue (C/D row = q*4+reg, col = l16)
    int rowl[8];
#pragma unroll
    for (int mi = 0; mi < 2; mi++)
#pragma unroll
        for (int r = 0; r < 4; r++) rowl[mi * 4 + r] = m0 + wm + mi * 16 + q * 4 + r;

    // ---- t = 0: h = tanh(proj[x[:,0]]) (h_prev = 0, no recurrent term)
    {
        float pv[8][4];
#pragma unroll
        for (int i = 0; i < 8; i++) {
            const int tok = x[rowl[i] * SEN + 0];
            const float* pr = proj + tok * HID + n0;
#pragma unroll
            for (int ni = 0; ni < 4; ni++) pv[i][ni] = pr[ni * 16 + l16];
        }
#pragma unroll
        for (int i = 0; i < 8; i++)
#pragma unroll
            for (int ni = 0; ni < 4; ni++)
                hbuf[rowl[i] * HID + n0 + ni * 16 + l16] = (bf16_t)fast_tanh(pv[i][ni]);
    }
    grid_sync_slot(sync_cnt);   // step-0 writes visible everywhere; B-DMA drained

#pragma unroll 1
    for (int t = 1; t < SEN; t++) {
        const bf16_t* h_in  = hbuf + (size_t)((t + 1) & 1) * (BATCH * HID);
        bf16_t*       h_out = hbuf + (size_t)(t & 1) * (BATCH * HID);

        // tokens for this step (issued first; L2-hot, hidden under A prefetch)
        int tk[8];
#pragma unroll
        for (int i = 0; i < 8; i++) tk[i] = x[rowl[i] * SEN + t];

        floatx4 acc[2][4];
#pragma unroll
        for (int i = 0; i < 2; i++)
#pragma unroll
            for (int j = 0; j < 4; j++) acc[i][j] = (floatx4){0.f, 0.f, 0.f, 0.f};

        // A-fragment base: lane (q,l16) holds h_in[row][k*32 + q*8 .. +7]
        const bf16_t* hA = h_in + (m0 + wm + l16) * HID + q * 8;
        bf16x8 af[2][8][2];   // [group buf][chunk][mi]

        ISSUE_AF(0, 0)
        ISSUE_AF(1, 8)
        COMPUTE_GROUP(0, 0)      // chunks 0..7
        ISSUE_AF(0, 16)
        COMPUTE_GROUP(1, 8)      // chunks 8..15
        ISSUE_AF(1, 24)

        // proj prefetch (tokens long since returned); lands before epilogue
        float pv[8][4];
#pragma unroll
        for (int i = 0; i < 8; i++) {
            const float* pr = proj + tk[i] * HID + n0;
#pragma unroll
            for (int ni = 0; ni < 4; ni++) pv[i][ni] = pr[ni * 16 + l16];
        }

        COMPUTE_GROUP(0, 16)     // chunks 16..23
        COMPUTE_GROUP(1, 24)     // chunks 24..31

        // epilogue: + proj, tanh, store
#pragma unroll
        for (int mi = 0; mi < 2; mi++)
#pragma unroll
            for (int r = 0; r < 4; r++)
#pragma unroll
                for (int ni = 0; ni < 4; ni++) {
                    float v = acc[mi][ni][r] + pv[mi * 4 + r][ni];
                    h_out[rowl[mi * 4 + r] * HID + n0 + ni * 16 + l16] = (bf16_t)fast_tanh(v);
                }

        if (t < SEN - 1) grid_sync_slot(sync_cnt + t * 16);   // none after final step
    }
}

#undef ISSUE_AF
#undef COMPUTE_GROUP

// ---------------- classifier: out = h @ W_cls^T + b_cls via MFMA (proven R2) ----------------
#define CBM 128
#define CLDK 72
__global__ __launch_bounds__(256)
void classifier_mfma(const bf16_t* __restrict__ h, const bf16_t* __restrict__ wcls,
                     const float* __restrict__ bcls, float* __restrict__ out)
{
    __shared__ __align__(16) bf16_t Ash[CBM][CLDK];
    __shared__ __align__(16) bf16_t Bsh[80][CLDK];

    const int tid = threadIdx.x;
    const int m0 = blockIdx.x * CBM;
    const int wave = tid >> 6, lane = tid & 63;
    const int wm = wave * 32;
    const int q = lane >> 4, l16 = lane & 15;

    floatx4 acc[2][5];
#pragma unroll
    for (int i = 0; i < 2; i++)
#pragma unroll
        for (int j = 0; j < 5; j++) acc[i][j] = (floatx4){0.f, 0.f, 0.f, 0.f};

    for (int kk = 0; kk < HID; kk += 64) {
#pragma unroll
        for (int it = 0; it < 4; it++) {
            int idx = tid + it * 256, r = idx >> 3, c = (idx & 7) * 8;
            *(uint4*)&Ash[r][c] = *(const uint4*)&h[(m0 + r) * HID + kk + c];
        }
#pragma unroll
        for (int it = 0; it < 3; it++) {
            int idx = tid + it * 256;
            if (idx < 640) {
                int r = idx >> 3, c = (idx & 7) * 8;
                *(uint4*)&Bsh[r][c] = *(const uint4*)&wcls[r * HID + kk + c];
            }
        }
        __syncthreads();
#pragma unroll
        for (int ks = 0; ks < 64; ks += 32) {
            bf16x8 af[2], bfr[5];
#pragma unroll
            for (int mi = 0; mi < 2; mi++)
                af[mi] = *(const bf16x8*)&Ash[wm + mi * 16 + l16][ks + q * 8];
#pragma unroll
            for (int ni = 0; ni < 5; ni++)
                bfr[ni] = *(const bf16x8*)&Bsh[ni * 16 + l16][ks + q * 8];
#pragma unroll
            for (int mi = 0; mi < 2; mi++)
#pragma unroll
                for (int ni = 0; ni < 5; ni++)
                    acc[mi][ni] = __builtin_amdgcn_mfma_f32_16x16x32_bf16(
                        af[mi], bfr[ni], acc[mi][ni], 0, 0, 0);
        }
        __syncthreads();
    }

#pragma unroll
    for (int mi = 0; mi < 2; mi++) {
#pragma unroll
        for (int r = 0; r < 4; r++) {
            int gm = m0 + wm + mi * 16 + q * 4 + r;
#pragma unroll
            for (int ni = 0; ni < 5; ni++) {
                int gn = ni * 16 + l16;
                if (gn < SEN + 1)
                    out[gm * (SEN + 1) + gn] = acc[mi][ni][r] + bcls[gn];
            }
        }
    }
}

extern "C" void kernel_launch(void* const* d_in, const int* in_sizes, int n_in,
                              void* d_out, int out_size, void* d_ws, size_t ws_size,
                              hipStream_t stream)
{
    const int*   x     = (const int*)  d_in[0];
    const float* emb   = (const float*)d_in[1];
    const float* w_ih  = (const float*)d_in[2];
    const float* w_hh  = (const float*)d_in[3];
    const float* w_cls = (const float*)d_in[4];
    const float* b_cls = (const float*)d_in[5];
    float* out = (float*)d_out;

    char* ws = (char*)d_ws;
    bf16_t* whh_bf  = (bf16_t*)ws;                                  // 2 MB
    float*  proj    = (float*)(ws + (2u << 20));                    // 128 KB
    bf16_t* wcls_bf = (bf16_t*)(ws + (2u << 20) + (128u << 10));    // 160 KB
    bf16_t* h0      = (bf16_t*)(ws + (2u << 20) + (288u << 10));    // 4 MB
    bf16_t* h1      = (bf16_t*)(ws + (6u << 20) + (288u << 10));    // 4 MB
    int*    scnt    = (int*)   (ws + (10u << 20) + (288u << 10));   // 4 KB (64 slots x 64B)

    hipMemsetAsync(scnt, 0, SEN * 16 * sizeof(int), stream);
    cvt_whh<<<(HID * HID) / 256, 256, 0, stream>>>(w_hh, whh_bf, HID * HID);
    proj_kernel<<<(VOCAB * HID + 255) / 256, 256, 0, stream>>>(emb, w_ih, proj);
    cvt_wcls<<<(80 * HID) / 256, 256, 0, stream>>>(w_cls, wcls_bf);

    dim3 grid(BATCH / BM, HID / BN);   // (16,16) = 256 blocks = 1/CU (128 KB LDS)
    rnn_persist<<<grid, 256, 0, stream>>>(whh_bf, proj, x, h0, scnt);

    classifier_mfma<<<BATCH / CBM, 256, 0, stream>>>(h1, wcls_bf, b_cls, out);
}

// Round 3
// 819.740 us; speedup vs baseline: 2.0623x; 2.0623x over previous
//
#include <hip/hip_runtime.h>
#include <hip/hip_bf16.h>

#define VOCAB 29
#define VEC   512
#define HID   1024
#define SEN   64
#define BATCH 2048

typedef __bf16 bf16_t;
typedef bf16_t bf16x8 __attribute__((ext_vector_type(8)));
typedef float  floatx4 __attribute__((ext_vector_type(4)));

// ---------------- prep: W_hh fp32 -> bf16 ----------------
__global__ void cvt_whh(const float* __restrict__ w, bf16_t* __restrict__ o, int n) {
    int i = blockIdx.x * blockDim.x + threadIdx.x;
    if (i < n) o[i] = (bf16_t)w[i];
}

// ---------------- prep: W_cls fp32 [65][1024] -> bf16 padded [80][1024] ----------------
__global__ void cvt_wcls(const float* __restrict__ w, bf16_t* __restrict__ o) {
    int i = blockIdx.x * blockDim.x + threadIdx.x;
    if (i >= 80 * HID) return;
    o[i] = (i < 65 * HID) ? (bf16_t)w[i] : (bf16_t)0.0f;
}

// ---------------- prep: proj[v][h] = dot(emb[v], W_ih[h]) (fp32) ----------------
__global__ void proj_kernel(const float* __restrict__ emb, const float* __restrict__ wih,
                            float* __restrict__ proj) {
    int idx = blockIdx.x * blockDim.x + threadIdx.x;
    if (idx >= VOCAB * HID) return;
    int v = idx / HID, h = idx % HID;
    const float* e = emb + v * VEC;
    const float* w = wih + h * VEC;
    float s = 0.f;
    for (int k = 0; k < VEC; k += 4) {
        float4 ev = *(const float4*)(e + k);
        float4 wv = *(const float4*)(w + k);
        s += ev.x * wv.x + ev.y * wv.y + ev.z * wv.z + ev.w * wv.w;
    }
    proj[idx] = s;
}

// exact identity tanh(x) = 1 - 2/(exp(2x)+1); fp32 rounding error << bf16 ulp
__device__ __forceinline__ float fast_tanh(float x) {
    float e = __expf(2.0f * x);
    return 1.0f - 2.0f / (e + 1.0f);
}

// async global->LDS 16B copy. LDS dest: wave-uniform base + lane*16 (HW rule).
__device__ __forceinline__ void load16_to_lds(const bf16_t* g, bf16_t* l) {
    auto gp = reinterpret_cast<const __attribute__((address_space(1))) unsigned int*>(
        reinterpret_cast<uintptr_t>(g));
    auto lp = reinterpret_cast<__attribute__((address_space(3))) unsigned int*>(
        static_cast<unsigned int>(reinterpret_cast<uintptr_t>(l)));
    __builtin_amdgcn_global_load_lds(gp, lp, 16, 0, 0);
}

// ============================================================================
// v4: PERSISTENT RNN with PANEL-SCOPED sync (the v3 fix).
//   Dependency is column-local: block (bx,by) at step t+1 reads only rows
//   produced by the 16 blocks sharing bx. Those 16 blocks have linear id
//   ≡ bx (mod 8) -> same XCD, same L2 (measured round-robin dispatch).
//   FAST sync: relaxed agent atomics (no buffer_wbl2 / no L2 inv — v3's 26
//   µs/step killer) + __syncthreads vmcnt-drain (stores reach L2 through
//   write-through L1) + one L1-only `buffer_inv` per step (h lines from t-2
//   are stale in L1; L2 is fresh).
//   GUARD: blocks publish HW_REG_XCC_ID into a per-panel mask before one
//   fully-safe acquire/release sync; if a panel spans XCDs (mapping changed),
//   fall back to acquire/release per-step sync — slow but correct anywhere.
// ============================================================================
#define BM 128
#define BN 64
#define PANEL_BLKS 16

__device__ __forceinline__ void panel_sync(int* cnt, int target, int safe) {
    __syncthreads();   // emits s_waitcnt vmcnt(0) lgkmcnt(0) + s_barrier:
                       // all this block's h stores are in L2 before the add
    if (threadIdx.x == 0) {
        if (safe) {    // cross-XCD fallback: full release/acquire semantics
            __hip_atomic_fetch_add(cnt, 1, __ATOMIC_RELEASE, __HIP_MEMORY_SCOPE_AGENT);
            while (__hip_atomic_load(cnt, __ATOMIC_ACQUIRE, __HIP_MEMORY_SCOPE_AGENT) < target)
                __builtin_amdgcn_s_sleep(1);
        } else {       // same-L2 fast path: no cache maintenance at all
            __hip_atomic_fetch_add(cnt, 1, __ATOMIC_RELAXED, __HIP_MEMORY_SCOPE_AGENT);
            while (__hip_atomic_load(cnt, __ATOMIC_RELAXED, __HIP_MEMORY_SCOPE_AGENT) < target)
                __builtin_amdgcn_s_sleep(1);
        }
    }
    __syncthreads();
    // invalidate this CU's vector L1 so step-t data is re-read from (fresh) L2
    asm volatile("buffer_inv" ::: "memory");
}

#define ISSUE_AF(BUF, KBASE)                                                     \
    _Pragma("unroll")                                                            \
    for (int j = 0; j < 8; j++) {                                                \
        af[BUF][j][0] = *(const bf16x8*)(hA + ((KBASE) + j) * 32);               \
        af[BUF][j][1] = *(const bf16x8*)(hA + 16 * HID + ((KBASE) + j) * 32);    \
    }

#define COMPUTE_GROUP(BUF, KBASE)                                                \
    _Pragma("unroll")                                                            \
    for (int j = 0; j < 8; j++) {                                                \
        const int p = (4 * ((KBASE) + j) + q) ^ l7;  /* phys 16B chunk in row */ \
        bf16x8 b0 = *(const bf16x8*)&Bsh[l16][p * 8];                            \
        bf16x8 b1 = *(const bf16x8*)&Bsh[16 + l16][p * 8];                       \
        bf16x8 b2 = *(const bf16x8*)&Bsh[32 + l16][p * 8];                       \
        bf16x8 b3 = *(const bf16x8*)&Bsh[48 + l16][p * 8];                       \
        acc[0][0] = __builtin_amdgcn_mfma_f32_16x16x32_bf16(af[BUF][j][0], b0, acc[0][0], 0, 0, 0); \
        acc[0][1] = __builtin_amdgcn_mfma_f32_16x16x32_bf16(af[BUF][j][0], b1, acc[0][1], 0, 0, 0); \
        acc[0][2] = __builtin_amdgcn_mfma_f32_16x16x32_bf16(af[BUF][j][0], b2, acc[0][2], 0, 0, 0); \
        acc[0][3] = __builtin_amdgcn_mfma_f32_16x16x32_bf16(af[BUF][j][0], b3, acc[0][3], 0, 0, 0); \
        acc[1][0] = __builtin_amdgcn_mfma_f32_16x16x32_bf16(af[BUF][j][1], b0, acc[1][0], 0, 0, 0); \
        acc[1][1] = __builtin_amdgcn_mfma_f32_16x16x32_bf16(af[BUF][j][1], b1, acc[1][1], 0, 0, 0); \
        acc[1][2] = __builtin_amdgcn_mfma_f32_16x16x32_bf16(af[BUF][j][1], b2, acc[1][2], 0, 0, 0); \
        acc[1][3] = __builtin_amdgcn_mfma_f32_16x16x32_bf16(af[BUF][j][1], b3, acc[1][3], 0, 0, 0); \
    }

__global__ __launch_bounds__(256, 1)
void rnn_persist(const bf16_t* __restrict__ whh, const float* __restrict__ proj,
                 const int* __restrict__ x, bf16_t* hbuf, int* scnt)
{
    __shared__ __align__(16) bf16_t Bsh[BN][HID];   // exactly 128 KB -> 1 block/CU
    __shared__ int uni_sh;

    const int tid  = threadIdx.x;
    const int m0   = blockIdx.x * BM;
    const int n0   = blockIdx.y * BN;
    const int wave = tid >> 6;
    const int lane = tid & 63;
    const int wm   = wave * 32;        // 4 waves split m: wave tile 32 x 64
    const int q    = lane >> 4;
    const int l16  = lane & 15;
    const int l7   = l16 & 7;

    int* cnt   = scnt + blockIdx.x * 64;                 // per-panel monotonic counter
    int* xmask = scnt + (16 + blockIdx.x) * 64;          // per-panel XCD mask

    // ---- stage W_hh slice ONCE (async DMA; drained by the first sync's barrier).
    //      Dest lane-linear (DMA rule), source chunk XOR'd: phys = glob ^ (r&7).
#pragma unroll
    for (int half = 0; half < 2; half++)
#pragma unroll
        for (int it = 0; it < 16; it++) {
            const int r = it * 4 + wave;
            load16_to_lds(whh + (n0 + r) * HID + half * 512 + (lane ^ (r & 7)) * 8,
                          &Bsh[r][half * 512 + lane * 8]);
        }

    // rows this lane owns (C/D row = q*4+reg, col = l16)
    int rowl[8];
#pragma unroll
    for (int mi = 0; mi < 2; mi++)
#pragma unroll
        for (int r = 0; r < 4; r++) rowl[mi * 4 + r] = m0 + wm + mi * 16 + q * 4 + r;

    // ---- t = 0: h = tanh(proj[x[:,0]]) (h_prev = 0)
    {
        float pv[8][4];
#pragma unroll
        for (int i = 0; i < 8; i++) {
            const int tok = x[rowl[i] * SEN + 0];
            const float* pr = proj + tok * HID + n0;
#pragma unroll
            for (int ni = 0; ni < 4; ni++) pv[i][ni] = pr[ni * 16 + l16];
        }
#pragma unroll
        for (int i = 0; i < 8; i++)
#pragma unroll
            for (int ni = 0; ni < 4; ni++)
                hbuf[rowl[i] * HID + n0 + ni * 16 + l16] = (bf16_t)fast_tanh(pv[i][ni]);
    }

    // ---- first sync: ALWAYS safe (release/acquire), also publishes XCD mask
    __syncthreads();   // drains t0 stores AND the B-DMA (vmcnt covers global_load_lds)
    if (tid == 0) {
        const int my_xcd = (int)__builtin_amdgcn_s_getreg((3 << 11) | 20);  // HW_REG_XCC_ID, 4 bits
        __hip_atomic_fetch_or(xmask, 1 << my_xcd, __ATOMIC_RELAXED, __HIP_MEMORY_SCOPE_AGENT);
        __hip_atomic_fetch_add(cnt, 1, __ATOMIC_RELEASE, __HIP_MEMORY_SCOPE_AGENT);
        while (__hip_atomic_load(cnt, __ATOMIC_ACQUIRE, __HIP_MEMORY_SCOPE_AGENT) < PANEL_BLKS)
            __builtin_amdgcn_s_sleep(1);
        const int m = __hip_atomic_load(xmask, __ATOMIC_RELAXED, __HIP_MEMORY_SCOPE_AGENT);
        uni_sh = ((m & (m - 1)) == 0);   // one XCD bit set -> fast path legal
    }
    __syncthreads();
    asm volatile("buffer_inv" ::: "memory");
    const int safe = !uni_sh;

#pragma unroll 1
    for (int t = 1; t < SEN; t++) {
        const bf16_t* h_in  = hbuf + (size_t)((t + 1) & 1) * (BATCH * HID);
        bf16_t*       h_out = hbuf + (size_t)(t & 1) * (BATCH * HID);

        int tk[8];
#pragma unroll
        for (int i = 0; i < 8; i++) tk[i] = x[rowl[i] * SEN + t];

        floatx4 acc[2][4];
#pragma unroll
        for (int i = 0; i < 2; i++)
#pragma unroll
            for (int j = 0; j < 4; j++) acc[i][j] = (floatx4){0.f, 0.f, 0.f, 0.f};

        // A-fragment base: lane (q,l16) holds h_in[row][k*32 + q*8 .. +7]
        const bf16_t* hA = h_in + (m0 + wm + l16) * HID + q * 8;
        bf16x8 af[2][8][2];   // [group buf][chunk][mi]

        ISSUE_AF(0, 0)
        ISSUE_AF(1, 8)
        COMPUTE_GROUP(0, 0)      // chunks 0..7
        ISSUE_AF(0, 16)
        COMPUTE_GROUP(1, 8)      // chunks 8..15
        ISSUE_AF(1, 24)

        float pv[8][4];
#pragma unroll
        for (int i = 0; i < 8; i++) {
            const float* pr = proj + tk[i] * HID + n0;
#pragma unroll
            for (int ni = 0; ni < 4; ni++) pv[i][ni] = pr[ni * 16 + l16];
        }

        COMPUTE_GROUP(0, 16)     // chunks 16..23
        COMPUTE_GROUP(1, 24)     // chunks 24..31

#pragma unroll
        for (int mi = 0; mi < 2; mi++)
#pragma unroll
            for (int r = 0; r < 4; r++)
#pragma unroll
                for (int ni = 0; ni < 4; ni++) {
                    float v = acc[mi][ni][r] + pv[mi * 4 + r][ni];
                    h_out[rowl[mi * 4 + r] * HID + n0 + ni * 16 + l16] = (bf16_t)fast_tanh(v);
                }

        if (t < SEN - 1) panel_sync(cnt, PANEL_BLKS * (t + 1), safe);
        // after t=63: end-of-kernel release (HW-orchestrated) makes h visible
    }
}

#undef ISSUE_AF
#undef COMPUTE_GROUP

// ---------------- classifier: out = h @ W_cls^T + b_cls via MFMA (proven R2) ----------------
#define CBM 128
#define CLDK 72
__global__ __launch_bounds__(256)
void classifier_mfma(const bf16_t* __restrict__ h, const bf16_t* __restrict__ wcls,
                     const float* __restrict__ bcls, float* __restrict__ out)
{
    __shared__ __align__(16) bf16_t Ash[CBM][CLDK];
    __shared__ __align__(16) bf16_t Bsh[80][CLDK];

    const int tid = threadIdx.x;
    const int m0 = blockIdx.x * CBM;
    const int wave = tid >> 6, lane = tid & 63;
    const int wm = wave * 32;
    const int q = lane >> 4, l16 = lane & 15;

    floatx4 acc[2][5];
#pragma unroll
    for (int i = 0; i < 2; i++)
#pragma unroll
        for (int j = 0; j < 5; j++) acc[i][j] = (floatx4){0.f, 0.f, 0.f, 0.f};

    for (int kk = 0; kk < HID; kk += 64) {
#pragma unroll
        for (int it = 0; it < 4; it++) {
            int idx = tid + it * 256, r = idx >> 3, c = (idx & 7) * 8;
            *(uint4*)&Ash[r][c] = *(const uint4*)&h[(m0 + r) * HID + kk + c];
        }
#pragma unroll
        for (int it = 0; it < 3; it++) {
            int idx = tid + it * 256;
            if (idx < 640) {
                int r = idx >> 3, c = (idx & 7) * 8;
                *(uint4*)&Bsh[r][c] = *(const uint4*)&wcls[r * HID + kk + c];
            }
        }
        __syncthreads();
#pragma unroll
        for (int ks = 0; ks < 64; ks += 32) {
            bf16x8 af[2], bfr[5];
#pragma unroll
            for (int mi = 0; mi < 2; mi++)
                af[mi] = *(const bf16x8*)&Ash[wm + mi * 16 + l16][ks + q * 8];
#pragma unroll
            for (int ni = 0; ni < 5; ni++)
                bfr[ni] = *(const bf16x8*)&Bsh[ni * 16 + l16][ks + q * 8];
#pragma unroll
            for (int mi = 0; mi < 2; mi++)
#pragma unroll
                for (int ni = 0; ni < 5; ni++)
                    acc[mi][ni] = __builtin_amdgcn_mfma_f32_16x16x32_bf16(
                        af[mi], bfr[ni], acc[mi][ni], 0, 0, 0);
        }
        __syncthreads();
    }

#pragma unroll
    for (int mi = 0; mi < 2; mi++) {
#pragma unroll
        for (int r = 0; r < 4; r++) {
            int gm = m0 + wm + mi * 16 + q * 4 + r;
#pragma unroll
            for (int ni = 0; ni < 5; ni++) {
                int gn = ni * 16 + l16;
                if (gn < SEN + 1)
                    out[gm * (SEN + 1) + gn] = acc[mi][ni][r] + bcls[gn];
            }
        }
    }
}

extern "C" void kernel_launch(void* const* d_in, const int* in_sizes, int n_in,
                              void* d_out, int out_size, void* d_ws, size_t ws_size,
                              hipStream_t stream)
{
    const int*   x     = (const int*)  d_in[0];
    const float* emb   = (const float*)d_in[1];
    const float* w_ih  = (const float*)d_in[2];
    const float* w_hh  = (const float*)d_in[3];
    const float* w_cls = (const float*)d_in[4];
    const float* b_cls = (const float*)d_in[5];
    float* out = (float*)d_out;

    char* ws = (char*)d_ws;
    bf16_t* whh_bf  = (bf16_t*)ws;                                  // 2 MB
    float*  proj    = (float*)(ws + (2u << 20));                    // 128 KB
    bf16_t* wcls_bf = (bf16_t*)(ws + (2u << 20) + (128u << 10));    // 160 KB
    bf16_t* h0      = (bf16_t*)(ws + (2u << 20) + (288u << 10));    // 4 MB
    bf16_t* h1      = (bf16_t*)(ws + (6u << 20) + (288u << 10));    // 4 MB
    int*    scnt    = (int*)   (ws + (10u << 20) + (288u << 10));   // 8 KB (16 cnt + 16 mask, 256B stride)

    hipMemsetAsync(scnt, 0, 32 * 64 * sizeof(int), stream);
    cvt_whh<<<(HID * HID) / 256, 256, 0, stream>>>(w_hh, whh_bf, HID * HID);
    proj_kernel<<<(VOCAB * HID + 255) / 256, 256, 0, stream>>>(emb, w_ih, proj);
    cvt_wcls<<<(80 * HID) / 256, 256, 0, stream>>>(w_cls, wcls_bf);

    dim3 grid(BATCH / BM, HID / BN);   // (16,16) = 256 blocks = 1/CU (128 KB LDS)
    rnn_persist<<<grid, 256, 0, stream>>>(whh_bf, proj, x, h0, scnt);

    classifier_mfma<<<BATCH / CBM, 256, 0, stream>>>(h1, wcls_bf, b_cls, out);
}

// Round 4
// 756.852 us; speedup vs baseline: 2.2337x; 1.0831x over previous
//
#include <hip/hip_runtime.h>
#include <hip/hip_bf16.h>

#define VOCAB 29
#define VEC   512
#define HID   1024
#define SEN   64
#define BATCH 2048

typedef __bf16 bf16_t;
typedef bf16_t bf16x8 __attribute__((ext_vector_type(8)));
typedef float  floatx4 __attribute__((ext_vector_type(4)));

// ---------------- prep: W_hh fp32 -> bf16 ----------------
__global__ void cvt_whh(const float* __restrict__ w, bf16_t* __restrict__ o, int n) {
    int i = blockIdx.x * blockDim.x + threadIdx.x;
    if (i < n) o[i] = (bf16_t)w[i];
}

// ---------------- prep: W_cls fp32 [65][1024] -> bf16 padded [80][1024] ----------------
__global__ void cvt_wcls(const float* __restrict__ w, bf16_t* __restrict__ o) {
    int i = blockIdx.x * blockDim.x + threadIdx.x;
    if (i >= 80 * HID) return;
    o[i] = (i < 65 * HID) ? (bf16_t)w[i] : (bf16_t)0.0f;
}

// ---------------- prep: proj[v][h] = dot(emb[v], W_ih[h]) (fp32) ----------------
__global__ void proj_kernel(const float* __restrict__ emb, const float* __restrict__ wih,
                            float* __restrict__ proj) {
    int idx = blockIdx.x * blockDim.x + threadIdx.x;
    if (idx >= VOCAB * HID) return;
    int v = idx / HID, h = idx % HID;
    const float* e = emb + v * VEC;
    const float* w = wih + h * VEC;
    float s = 0.f;
    for (int k = 0; k < VEC; k += 4) {
        float4 ev = *(const float4*)(e + k);
        float4 wv = *(const float4*)(w + k);
        s += ev.x * wv.x + ev.y * wv.y + ev.z * wv.z + ev.w * wv.w;
    }
    proj[idx] = s;
}

// exact identity tanh(x) = 1 - 2/(exp(2x)+1); fp32 rounding error << bf16 ulp
__device__ __forceinline__ float fast_tanh(float x) {
    float e = __expf(2.0f * x);
    return 1.0f - 2.0f / (e + 1.0f);
}

// async global->LDS 16B copy. LDS dest: wave-uniform base + lane*16 (HW rule).
__device__ __forceinline__ void load16_to_lds(const bf16_t* g, bf16_t* l) {
    auto gp = reinterpret_cast<const __attribute__((address_space(1))) unsigned int*>(
        reinterpret_cast<uintptr_t>(g));
    auto lp = reinterpret_cast<__attribute__((address_space(3))) unsigned int*>(
        static_cast<unsigned int>(reinterpret_cast<uintptr_t>(l)));
    __builtin_amdgcn_global_load_lds(gp, lp, 16, 0, 0);
}

// ============================================================================
// v5: v4's persistent structure + (a) sched_barrier-PINNED A-prefetch pipeline
// (v4's 148 VGPR proved the compiler sank the af[2][8][2] double-buffer loads
// next to their uses -> every compute group ate a raw L2 round trip) and
// (b) flag-based panel sync: plain stores + relaxed agent loads (sc0, served
// by the panel-local XCD L2) instead of far agent-RMW atomics.
// pv/tk loads hoisted off the critical path (tk prefetched a step ahead).
// ============================================================================
#define BM 128
#define BN 64
#define PANEL_BLKS 16
#define SB() __builtin_amdgcn_sched_barrier(0)

#define ISSUE_AF(BUF, KBASE)                                                     \
    _Pragma("unroll")                                                            \
    for (int j = 0; j < 8; j++) {                                                \
        af[BUF][j][0] = *(const bf16x8*)(hA + ((KBASE) + j) * 32);               \
        af[BUF][j][1] = *(const bf16x8*)(hA + 16 * HID + ((KBASE) + j) * 32);    \
    }

#define COMPUTE_GROUP(BUF, KBASE)                                                \
    _Pragma("unroll")                                                            \
    for (int j = 0; j < 8; j++) {                                                \
        const int p = (4 * ((KBASE) + j) + q) ^ l7;  /* phys 16B chunk in row */ \
        bf16x8 b0 = *(const bf16x8*)&Bsh[l16][p * 8];                            \
        bf16x8 b1 = *(const bf16x8*)&Bsh[16 + l16][p * 8];                       \
        bf16x8 b2 = *(const bf16x8*)&Bsh[32 + l16][p * 8];                       \
        bf16x8 b3 = *(const bf16x8*)&Bsh[48 + l16][p * 8];                       \
        acc[0][0] = __builtin_amdgcn_mfma_f32_16x16x32_bf16(af[BUF][j][0], b0, acc[0][0], 0, 0, 0); \
        acc[0][1] = __builtin_amdgcn_mfma_f32_16x16x32_bf16(af[BUF][j][0], b1, acc[0][1], 0, 0, 0); \
        acc[0][2] = __builtin_amdgcn_mfma_f32_16x16x32_bf16(af[BUF][j][0], b2, acc[0][2], 0, 0, 0); \
        acc[0][3] = __builtin_amdgcn_mfma_f32_16x16x32_bf16(af[BUF][j][0], b3, acc[0][3], 0, 0, 0); \
        acc[1][0] = __builtin_amdgcn_mfma_f32_16x16x32_bf16(af[BUF][j][1], b0, acc[1][0], 0, 0, 0); \
        acc[1][1] = __builtin_amdgcn_mfma_f32_16x16x32_bf16(af[BUF][j][1], b1, acc[1][1], 0, 0, 0); \
        acc[1][2] = __builtin_amdgcn_mfma_f32_16x16x32_bf16(af[BUF][j][1], b2, acc[1][2], 0, 0, 0); \
        acc[1][3] = __builtin_amdgcn_mfma_f32_16x16x32_bf16(af[BUF][j][1], b3, acc[1][3], 0, 0, 0); \
    }

__global__ __launch_bounds__(256, 1)
void rnn_persist(const bf16_t* __restrict__ whh, const float* __restrict__ proj,
                 const int* __restrict__ x, bf16_t* hbuf, int* scnt)
{
    __shared__ __align__(16) bf16_t Bsh[BN][HID];   // exactly 128 KB -> 1 block/CU
    __shared__ int uni_sh;

    const int tid  = threadIdx.x;
    const int m0   = blockIdx.x * BM;
    const int n0   = blockIdx.y * BN;
    const int wave = tid >> 6;
    const int lane = tid & 63;
    const int wm   = wave * 32;        // 4 waves split m: wave tile 32 x 64
    const int q    = lane >> 4;
    const int l16  = lane & 15;
    const int l7   = l16 & 7;

    int* cnt   = scnt + blockIdx.x * 64;           // safe-path counter (256B stride)
    int* xmask = scnt + (16 + blockIdx.x) * 64;    // per-panel XCD mask
    int* fl    = scnt + 2048 + blockIdx.x * 64;    // fast-path flags: 16 ints, 256B stride/panel

    // ---- stage W_hh slice ONCE (async DMA; drained by the first sync's barrier).
#pragma unroll
    for (int half = 0; half < 2; half++)
#pragma unroll
        for (int it = 0; it < 16; it++) {
            const int r = it * 4 + wave;
            load16_to_lds(whh + (n0 + r) * HID + half * 512 + (lane ^ (r & 7)) * 8,
                          &Bsh[r][half * 512 + lane * 8]);
        }

    // rows this lane owns (C/D row = q*4+reg, col = l16)
    int rowl[8];
#pragma unroll
    for (int mi = 0; mi < 2; mi++)
#pragma unroll
        for (int r = 0; r < 4; r++) rowl[mi * 4 + r] = m0 + wm + mi * 16 + q * 4 + r;

    // ---- t = 0: h = tanh(proj[x[:,0]]) (h_prev = 0)
    {
        float pv0[8][4];
#pragma unroll
        for (int i = 0; i < 8; i++) {
            const int tok = x[rowl[i] * SEN + 0];
            const float* pr = proj + tok * HID + n0;
#pragma unroll
            for (int ni = 0; ni < 4; ni++) pv0[i][ni] = pr[ni * 16 + l16];
        }
#pragma unroll
        for (int i = 0; i < 8; i++)
#pragma unroll
            for (int ni = 0; ni < 4; ni++)
                hbuf[rowl[i] * HID + n0 + ni * 16 + l16] = (bf16_t)fast_tanh(pv0[i][ni]);
    }

    // tokens for t=1 (prefetched; x is constant data)
    int tk[8];
#pragma unroll
    for (int i = 0; i < 8; i++) tk[i] = x[rowl[i] * SEN + 1];

    // ---- first sync: ALWAYS safe (release/acquire), also publishes XCD mask
    __syncthreads();   // drains t0 stores AND the B-DMA (vmcnt covers global_load_lds)
    if (tid == 0) {
        const int my_xcd = (int)__builtin_amdgcn_s_getreg((3 << 11) | 20);  // HW_REG_XCC_ID
        __hip_atomic_fetch_or(xmask, 1 << my_xcd, __ATOMIC_RELAXED, __HIP_MEMORY_SCOPE_AGENT);
        __hip_atomic_fetch_add(cnt, 1, __ATOMIC_RELEASE, __HIP_MEMORY_SCOPE_AGENT);
        while (__hip_atomic_load(cnt, __ATOMIC_ACQUIRE, __HIP_MEMORY_SCOPE_AGENT) < PANEL_BLKS)
            __builtin_amdgcn_s_sleep(1);
        const int m = __hip_atomic_load(xmask, __ATOMIC_RELAXED, __HIP_MEMORY_SCOPE_AGENT);
        uni_sh = ((m & (m - 1)) == 0);   // one XCD bit set -> fast flag path legal
    }
    __syncthreads();
    asm volatile("buffer_inv" ::: "memory");
    const int safe = !uni_sh;

#pragma unroll 1
    for (int t = 1; t < SEN; t++) {
        const bf16_t* h_in  = hbuf + (size_t)((t + 1) & 1) * (BATCH * HID);
        bf16_t*       h_out = hbuf + (size_t)(t & 1) * (BATCH * HID);

        floatx4 acc[2][4];
#pragma unroll
        for (int i = 0; i < 2; i++)
#pragma unroll
            for (int j = 0; j < 4; j++) acc[i][j] = (floatx4){0.f, 0.f, 0.f, 0.f};

        // A-fragment base: lane (q,l16) holds h_in[row][k*32 + q*8 .. +7]
        const bf16_t* hA = h_in + (m0 + wm + l16) * HID + q * 8;
        bf16x8 af[2][8][2];   // [group buf][chunk][mi] — 128 VGPR, budget is 512 (1 wave/SIMD)

        // ---- pinned software pipeline -------------------------------------
        ISSUE_AF(0, 0)               // 16 loads -> af0
        ISSUE_AF(1, 8)               // 16 loads -> af1
        // proj rows for THIS step (tk prefetched last step); used ~2000 cyc later
        float pv[8][4];
#pragma unroll
        for (int i = 0; i < 8; i++) {
            const float* pr = proj + tk[i] * HID + n0;
#pragma unroll
            for (int ni = 0; ni < 4; ni++) pv[i][ni] = pr[ni * 16 + l16];
        }
        SB();
        COMPUTE_GROUP(0, 0)          // chunks 0..7   (waits af0 only)
        SB();
        ISSUE_AF(0, 16)              // refill af0
        SB();
        COMPUTE_GROUP(1, 8)          // chunks 8..15
        SB();
        ISSUE_AF(1, 24)              // refill af1
        if (t < SEN - 1) {           // tokens for t+1 (off critical path)
#pragma unroll
            for (int i = 0; i < 8; i++) tk[i] = x[rowl[i] * SEN + t + 1];
        }
        SB();
        COMPUTE_GROUP(0, 16)         // chunks 16..23
        SB();
        COMPUTE_GROUP(1, 24)         // chunks 24..31
        SB();

        // epilogue: + proj, tanh, store
#pragma unroll
        for (int mi = 0; mi < 2; mi++)
#pragma unroll
            for (int r = 0; r < 4; r++)
#pragma unroll
                for (int ni = 0; ni < 4; ni++) {
                    float v = acc[mi][ni][r] + pv[mi * 4 + r][ni];
                    h_out[rowl[mi * 4 + r] * HID + n0 + ni * 16 + l16] = (bf16_t)fast_tanh(v);
                }

        // ---- panel sync (skip after final step) ---------------------------
        if (t < SEN - 1) {
            __syncthreads();   // vmcnt(0): this block's h stores are in L2
            if (safe) {        // cross-XCD fallback: full release/acquire counter
                if (tid == 0) {
                    __hip_atomic_fetch_add(cnt, 1, __ATOMIC_RELEASE, __HIP_MEMORY_SCOPE_AGENT);
                    while (__hip_atomic_load(cnt, __ATOMIC_ACQUIRE, __HIP_MEMORY_SCOPE_AGENT)
                           < PANEL_BLKS * (t + 1))
                        __builtin_amdgcn_s_sleep(1);
                }
            } else {           // same-L2 fast path: flag store + sc0 poll, all in-XCD
                if (tid == 0)
                    __hip_atomic_store(&fl[blockIdx.y], t,
                                       __ATOMIC_RELAXED, __HIP_MEMORY_SCOPE_AGENT);
                if (tid < 16) {
                    while (__hip_atomic_load(&fl[tid],
                                             __ATOMIC_RELAXED, __HIP_MEMORY_SCOPE_AGENT) < t) {}
                }
            }
            __syncthreads();
            // invalidate CU L1 so step-t h is re-read from (fresh) XCD L2
            asm volatile("buffer_inv" ::: "memory");
        }
    }
}

#undef ISSUE_AF
#undef COMPUTE_GROUP

// ---------------- classifier: out = h @ W_cls^T + b_cls via MFMA (proven R2) ----------------
#define CBM 128
#define CLDK 72
__global__ __launch_bounds__(256)
void classifier_mfma(const bf16_t* __restrict__ h, const bf16_t* __restrict__ wcls,
                     const float* __restrict__ bcls, float* __restrict__ out)
{
    __shared__ __align__(16) bf16_t Ash[CBM][CLDK];
    __shared__ __align__(16) bf16_t Bsh[80][CLDK];

    const int tid = threadIdx.x;
    const int m0 = blockIdx.x * CBM;
    const int wave = tid >> 6, lane = tid & 63;
    const int wm = wave * 32;
    const int q = lane >> 4, l16 = lane & 15;

    floatx4 acc[2][5];
#pragma unroll
    for (int i = 0; i < 2; i++)
#pragma unroll
        for (int j = 0; j < 5; j++) acc[i][j] = (floatx4){0.f, 0.f, 0.f, 0.f};

    for (int kk = 0; kk < HID; kk += 64) {
#pragma unroll
        for (int it = 0; it < 4; it++) {
            int idx = tid + it * 256, r = idx >> 3, c = (idx & 7) * 8;
            *(uint4*)&Ash[r][c] = *(const uint4*)&h[(m0 + r) * HID + kk + c];
        }
#pragma unroll
        for (int it = 0; it < 3; it++) {
            int idx = tid + it * 256;
            if (idx < 640) {
                int r = idx >> 3, c = (idx & 7) * 8;
                *(uint4*)&Bsh[r][c] = *(const uint4*)&wcls[r * HID + kk + c];
            }
        }
        __syncthreads();
#pragma unroll
        for (int ks = 0; ks < 64; ks += 32) {
            bf16x8 af[2], bfr[5];
#pragma unroll
            for (int mi = 0; mi < 2; mi++)
                af[mi] = *(const bf16x8*)&Ash[wm + mi * 16 + l16][ks + q * 8];
#pragma unroll
            for (int ni = 0; ni < 5; ni++)
                bfr[ni] = *(const bf16x8*)&Bsh[ni * 16 + l16][ks + q * 8];
#pragma unroll
            for (int mi = 0; mi < 2; mi++)
#pragma unroll
                for (int ni = 0; ni < 5; ni++)
                    acc[mi][ni] = __builtin_amdgcn_mfma_f32_16x16x32_bf16(
                        af[mi], bfr[ni], acc[mi][ni], 0, 0, 0);
        }
        __syncthreads();
    }

#pragma unroll
    for (int mi = 0; mi < 2; mi++) {
#pragma unroll
        for (int r = 0; r < 4; r++) {
            int gm = m0 + wm + mi * 16 + q * 4 + r;
#pragma unroll
            for (int ni = 0; ni < 5; ni++) {
                int gn = ni * 16 + l16;
                if (gn < SEN + 1)
                    out[gm * (SEN + 1) + gn] = acc[mi][ni][r] + bcls[gn];
            }
        }
    }
}

extern "C" void kernel_launch(void* const* d_in, const int* in_sizes, int n_in,
                              void* d_out, int out_size, void* d_ws, size_t ws_size,
                              hipStream_t stream)
{
    const int*   x     = (const int*)  d_in[0];
    const float* emb   = (const float*)d_in[1];
    const float* w_ih  = (const float*)d_in[2];
    const float* w_hh  = (const float*)d_in[3];
    const float* w_cls = (const float*)d_in[4];
    const float* b_cls = (const float*)d_in[5];
    float* out = (float*)d_out;

    char* ws = (char*)d_ws;
    bf16_t* whh_bf  = (bf16_t*)ws;                                  // 2 MB
    float*  proj    = (float*)(ws + (2u << 20));                    // 128 KB
    bf16_t* wcls_bf = (bf16_t*)(ws + (2u << 20) + (128u << 10));    // 160 KB
    bf16_t* h0      = (bf16_t*)(ws + (2u << 20) + (288u << 10));    // 4 MB
    bf16_t* h1      = (bf16_t*)(ws + (6u << 20) + (288u << 10));    // 4 MB
    int*    scnt    = (int*)   (ws + (10u << 20) + (288u << 10));   // 16 KB sync area

    hipMemsetAsync(scnt, 0, 16384, stream);
    cvt_whh<<<(HID * HID) / 256, 256, 0, stream>>>(w_hh, whh_bf, HID * HID);
    proj_kernel<<<(VOCAB * HID + 255) / 256, 256, 0, stream>>>(emb, w_ih, proj);
    cvt_wcls<<<(80 * HID) / 256, 256, 0, stream>>>(w_cls, wcls_bf);

    dim3 grid(BATCH / BM, HID / BN);   // (16,16) = 256 blocks = 1/CU (128 KB LDS)
    rnn_persist<<<grid, 256, 0, stream>>>(whh_bf, proj, x, h0, scnt);

    classifier_mfma<<<BATCH / CBM, 256, 0, stream>>>(h1, wcls_bf, b_cls, out);
}